// Round 5
// baseline (329.025 us; speedup 1.0000x reference)
//
#include <hip/hip_runtime.h>
#include <math.h>
#include <stdint.h>

#define HDIM 1536
#define NUM_HEADS 12
#define NUM_KV 2
#define HEAD_DIM 128
#define GQA_REP 6
#define MAX_CACHE 131072
#define SCALE 0.08838834764831845f   // 128^-0.5

// workspace layout (float offsets)
#define WS_Q    0                     // 1536 floats (pre-scaled q)
#define WS_OUT  2048                  // 1536 floats (attention out, flat)
#define WS_L2   4096                  // 12*32*132 = 50688 floats
#define WS_PART 65536                 // 2048*6*132 = 1622016 floats
#define REC 132                       // per-partial record: [m, l, pad, pad, acc(128)]

#define UNITS_PER_G 1024              // 131072 / 128 positions per block-unit
#define NEG_BIG (-1.0e30f)
#define MASK_NEG (-1.0e38f)

#define GLOBAL_AS __attribute__((address_space(1)))
#define LDS_AS    __attribute__((address_space(3)))

// ---------------------------------------------------------------------------
// Kernel 1: fused QKV projection. 2048 rows, one row per wave.
// ---------------------------------------------------------------------------
__global__ __launch_bounds__(256) void proj_qkv(
    const float* __restrict__ x, const float* __restrict__ Wq,
    const float* __restrict__ Wk, const float* __restrict__ Wv,
    float* __restrict__ kv_k, float* __restrict__ kv_v,
    const int* __restrict__ pos_p, float* __restrict__ ws)
{
    int r    = (blockIdx.x * 256 + threadIdx.x) >> 6;   // 0..2047
    int lane = threadIdx.x & 63;

    const float* Wrow;
    if (r < HDIM)            Wrow = Wq + (size_t)r * HDIM;
    else if (r < HDIM + 256) Wrow = Wk + (size_t)(r - HDIM) * HDIM;
    else                     Wrow = Wv + (size_t)(r - HDIM - 256) * HDIM;

    const float4* w4 = (const float4*)Wrow;
    const float4* x4 = (const float4*)x;
    float sum = 0.f;
#pragma unroll
    for (int it = 0; it < 6; ++it) {
        float4 a = w4[lane + 64 * it];
        float4 b = x4[lane + 64 * it];
        sum += a.x * b.x + a.y * b.y + a.z * b.z + a.w * b.w;
    }
#pragma unroll
    for (int off = 32; off >= 1; off >>= 1) sum += __shfl_xor(sum, off);

    if (lane == 0) {
        if (r < HDIM) {
            ws[WS_Q + r] = sum * SCALE;
        } else {
            int pos = *pos_p;
            if (r < HDIM + 256) {
                int j = r - HDIM; int g = j >> 7, d = j & 127;
                kv_k[((size_t)g * MAX_CACHE + pos) * HEAD_DIM + d] = sum;
            } else {
                int j = r - HDIM - 256; int g = j >> 7, d = j & 127;
                kv_v[((size_t)g * MAX_CACHE + pos) * HEAD_DIM + d] = sum;
            }
        }
    }
}

// ---------------------------------------------------------------------------
// Kernel 2: flash-decode with async global->LDS staging.
// Block = 4 waves, 128 positions of one KV group, staged as 8 x 16-position
// tiles, double-buffered in LDS (K0,V0,K1,V1 = 8KB each, 32 KB total).
// Pipeline per stage: barrier (drains this stage's DMA; next stage not yet
// issued) -> issue next stage DMA -> compute from LDS. DMA for stage s+1 is
// in flight during compute of stage s; one barrier per stage.
// Per stage a wave computes 4 positions (half-wave h takes pos 4w+h, 4w+2+h)
// with the R4 batched online-softmax update. Merge scratch overlays buffer 0
// after the loop. LDS 32 KB -> 5 blocks/CU; DMA costs no VGPRs.
// ---------------------------------------------------------------------------
__global__ __launch_bounds__(256, 4) void attn_decode(
    const float* __restrict__ kv_k, const float* __restrict__ kv_v,
    const int* __restrict__ pos_p, float* __restrict__ ws)
{
    __shared__ char smem[32768];      // K0|V0|K1|V1 (8KB each); merge overlays

    int b    = blockIdx.x;          // 0..2047
    int g    = b >> 10;             // kv group
    int ublk = b & 1023;            // unit (block) within group
    int wid  = threadIdx.x >> 6;    // wave 0..3
    int lane = threadIdx.x & 63;
    int h    = lane >> 5;           // half (position low bit)
    int j    = lane & 31;           // float4 chunk within head_dim

    int seq_len = *pos_p + 1;
    if (seq_len > MAX_CACHE) seq_len = MAX_CACHE;

    // q fragments (pre-scaled)
    const float* qb = ws + WS_Q + g * (GQA_REP * HEAD_DIM);
    float4 q[GQA_REP];
#pragma unroll
    for (int r = 0; r < GQA_REP; ++r)
        q[r] = ((const float4*)(qb + r * HEAD_DIM))[j];

    float  m[GQA_REP], l[GQA_REP];
    float4 acc[GQA_REP];
#pragma unroll
    for (int r = 0; r < GQA_REP; ++r) {
        m[r] = NEG_BIG; l[r] = 0.f;
        acc[r].x = acc[r].y = acc[r].z = acc[r].w = 0.f;
    }

    int blkbase = ublk * 128;                 // block's 128 positions
    const float* Kg = kv_k + ((size_t)g * MAX_CACHE + blkbase) * HEAD_DIM;
    const float* Vg = kv_v + ((size_t)g * MAX_CACHE + blkbase) * HEAD_DIM;

    // --- stage DMA: 16 positions = 8 chunks of 1 KB for K, 8 for V.
    // wave wid issues chunks {wid, wid+4} of each. LDS dest is wave-uniform;
    // HW scatters lane i to dest + i*16.
    auto issue_stage = [&](int s) {
        int parity = s & 1;
#pragma unroll
        for (int cc = 0; cc < 2; ++cc) {
            int c = wid + 4 * cc;                      // chunk 0..7
            int p0 = s * 16 + 2 * c;                   // stage-local pos of chunk
            const char* gk = (const char*)(Kg + (size_t)p0 * HEAD_DIM) + lane * 16;
            const char* gv = (const char*)(Vg + (size_t)p0 * HEAD_DIM) + lane * 16;
            char* lk = smem + parity * 16384 + c * 1024;
            char* lv = smem + parity * 16384 + 8192 + c * 1024;
            __builtin_amdgcn_global_load_lds((const GLOBAL_AS void*)gk,
                                             (LDS_AS void*)lk, 16, 0, 0);
            __builtin_amdgcn_global_load_lds((const GLOBAL_AS void*)gv,
                                             (LDS_AS void*)lv, 16, 0, 0);
        }
    };

    issue_stage(0);

    for (int s = 0; s < 8; ++s) {
        __syncthreads();              // drains stage-s DMA (s+1 not yet issued)
        if (s < 7) issue_stage(s + 1);

        int parity = s & 1;
        int t0 = 4 * wid + h;         // stage-local position for pair A
        const float4* Kt = (const float4*)(smem + parity * 16384);
        const float4* Vt = (const float4*)(smem + parity * 16384 + 8192);
        float4 KA = Kt[t0 * 32 + j];
        float4 KB = Kt[(t0 + 2) * 32 + j];
        float4 VA = Vt[t0 * 32 + j];
        float4 VB = Vt[(t0 + 2) * 32 + j];

        int pA = blkbase + s * 16 + t0;
        float maskA = (pA     < seq_len) ? 0.f : MASK_NEG;
        float maskB = (pA + 2 < seq_len) ? 0.f : MASK_NEG;

#pragma unroll
        for (int r = 0; r < GQA_REP; ++r) {
            float sA = KA.x * q[r].x + KA.y * q[r].y + KA.z * q[r].z + KA.w * q[r].w;
            float sB = KB.x * q[r].x + KB.y * q[r].y + KB.z * q[r].z + KB.w * q[r].w;
#pragma unroll
            for (int off = 16; off >= 1; off >>= 1) {
                sA += __shfl_xor(sA, off);
                sB += __shfl_xor(sB, off);
            }
            sA += maskA; sB += maskB;

            float mn    = fmaxf(m[r], fmaxf(sA, sB));
            float alpha = __expf(m[r] - mn);
            float pa    = __expf(sA - mn);
            float pb    = __expf(sB - mn);
            l[r] = l[r] * alpha + pa + pb;
            acc[r].x = acc[r].x * alpha + pa * VA.x + pb * VB.x;
            acc[r].y = acc[r].y * alpha + pa * VA.y + pb * VB.y;
            acc[r].z = acc[r].z * alpha + pa * VA.z + pb * VB.z;
            acc[r].w = acc[r].w * alpha + pa * VA.w + pb * VB.w;
            m[r] = mn;
        }
    }

    // merge the two halves in-register, then park wave partials in LDS
    // (merge area overlays buffer 0 — safe after the barrier below).
    __syncthreads();
    float* mrg = (float*)smem;        // [4][GQA_REP][REC]
#pragma unroll
    for (int r = 0; r < GQA_REP; ++r) {
        float mo = __shfl_xor(m[r], 32);
        float lo = __shfl_xor(l[r], 32);
        float4 ao;
        ao.x = __shfl_xor(acc[r].x, 32);
        ao.y = __shfl_xor(acc[r].y, 32);
        ao.z = __shfl_xor(acc[r].z, 32);
        ao.w = __shfl_xor(acc[r].w, 32);
        float M  = fmaxf(m[r], mo);
        float a0 = __expf(m[r] - M);
        float a1 = __expf(mo   - M);
        float L  = l[r] * a0 + lo * a1;
        float4 A;
        A.x = acc[r].x * a0 + ao.x * a1;
        A.y = acc[r].y * a0 + ao.y * a1;
        A.z = acc[r].z * a0 + ao.z * a1;
        A.w = acc[r].w * a0 + ao.w * a1;

        float* rr = mrg + ((size_t)wid * GQA_REP + r) * REC;
        if (lane < 32) ((float4*)(rr + 4))[j] = A;
        if (lane == 0) { rr[0] = M; rr[1] = L; }
    }
    __syncthreads();

    // cross-wave merge: wave `wid` handles heads r = wid, wid+4
    for (int r = wid; r < GQA_REP; r += 4) {
        const float* r0 = mrg + (0 * GQA_REP + r) * REC;
        const float* r1 = mrg + (1 * GQA_REP + r) * REC;
        const float* r2 = mrg + (2 * GQA_REP + r) * REC;
        const float* r3 = mrg + (3 * GQA_REP + r) * REC;
        float m0 = r0[0], m1 = r1[0], m2 = r2[0], m3 = r3[0];
        float M = fmaxf(fmaxf(m0, m1), fmaxf(m2, m3));
        float w0 = __expf(m0 - M), w1 = __expf(m1 - M);
        float w2 = __expf(m2 - M), w3 = __expf(m3 - M);
        float L = r0[1] * w0 + r1[1] * w1 + r2[1] * w2 + r3[1] * w3;

        float2 a0v = ((const float2*)(r0 + 4))[lane];
        float2 a1v = ((const float2*)(r1 + 4))[lane];
        float2 a2v = ((const float2*)(r2 + 4))[lane];
        float2 a3v = ((const float2*)(r3 + 4))[lane];
        float2 a;
        a.x = a0v.x * w0 + a1v.x * w1 + a2v.x * w2 + a3v.x * w3;
        a.y = a0v.y * w0 + a1v.y * w1 + a2v.y * w2 + a3v.y * w3;

        float* rec = ws + WS_PART + ((size_t)(g * UNITS_PER_G + ublk) * GQA_REP + r) * REC;
        ((float2*)(rec + 4))[lane] = a;
        if (lane == 0) { rec[0] = M; rec[1] = L; }
    }
}

// ---------------------------------------------------------------------------
// Kernel 3: combine stage 1 — 12 heads x 32 slabs; each block merges 32 units.
// ---------------------------------------------------------------------------
__global__ __launch_bounds__(64) void combine1(float* __restrict__ ws)
{
    int b  = blockIdx.x;          // 0..383
    int hh = b >> 5;              // head 0..11
    int s  = b & 31;              // slab
    int g = hh / GQA_REP, r = hh % GQA_REP;
    int t  = threadIdx.x;         // 0..63
    int um = t & 31;

    const float* base = ws + WS_PART +
        ((size_t)(g * UNITS_PER_G + s * 32) * GQA_REP + r) * REC;
    const float* rec = base + (size_t)um * GQA_REP * REC;
    float mu = rec[0], lu = rec[1];

    float M = mu;
#pragma unroll
    for (int off = 16; off >= 1; off >>= 1) M = fmaxf(M, __shfl_xor(M, off));
    float w = __expf(mu - M);
    float L = lu * w;
#pragma unroll
    for (int off = 16; off >= 1; off >>= 1) L += __shfl_xor(L, off);

    float2 a; a.x = 0.f; a.y = 0.f;      // dims 2t, 2t+1
    for (int uu = 0; uu < 32; ++uu) {
        float wu = __shfl(w, uu);
        float2 av = ((const float2*)(base + (size_t)uu * GQA_REP * REC + 4))[t];
        a.x += wu * av.x;
        a.y += wu * av.y;
    }
    float* orec = ws + WS_L2 + (size_t)(hh * 32 + s) * REC;
    ((float2*)(orec + 4))[t] = a;
    if (t == 0) { orec[0] = M; orec[1] = L; }
}

// ---------------------------------------------------------------------------
// Kernel 4: combine stage 2 — 12 heads; merge 32 slab records, write out vec.
// ---------------------------------------------------------------------------
__global__ __launch_bounds__(64) void combine2(float* __restrict__ ws)
{
    int hh = blockIdx.x;          // 0..11
    int t  = threadIdx.x;
    int um = t & 31;

    const float* base = ws + WS_L2 + (size_t)(hh * 32) * REC;
    const float* rec  = base + (size_t)um * REC;
    float mu = rec[0], lu = rec[1];

    float M = mu;
#pragma unroll
    for (int off = 16; off >= 1; off >>= 1) M = fmaxf(M, __shfl_xor(M, off));
    float w = __expf(mu - M);
    float L = lu * w;
#pragma unroll
    for (int off = 16; off >= 1; off >>= 1) L += __shfl_xor(L, off);

    float2 a; a.x = 0.f; a.y = 0.f;
    for (int uu = 0; uu < 32; ++uu) {
        float wu = __shfl(w, uu);
        float2 av = ((const float2*)(base + (size_t)uu * REC + 4))[t];
        a.x += wu * av.x;
        a.y += wu * av.y;
    }
    float invL = 1.f / L;
    ws[WS_OUT + hh * HEAD_DIM + 2 * t]     = a.x * invL;
    ws[WS_OUT + hh * HEAD_DIM + 2 * t + 1] = a.y * invL;
}

// ---------------------------------------------------------------------------
// Kernel 5: output projection y = Wo @ out. One row per wave.
// ---------------------------------------------------------------------------
__global__ __launch_bounds__(256) void proj_out(
    const float* __restrict__ Wo, const float* __restrict__ ws,
    float* __restrict__ y)
{
    int r    = (blockIdx.x * 256 + threadIdx.x) >> 6;   // 0..1535
    int lane = threadIdx.x & 63;
    const float4* w4 = (const float4*)(Wo + (size_t)r * HDIM);
    const float4* o4 = (const float4*)(ws + WS_OUT);
    float sum = 0.f;
#pragma unroll
    for (int it = 0; it < 6; ++it) {
        float4 a = w4[lane + 64 * it];
        float4 b = o4[lane + 64 * it];
        sum += a.x * b.x + a.y * b.y + a.z * b.z + a.w * b.w;
    }
#pragma unroll
    for (int off = 32; off >= 1; off >>= 1) sum += __shfl_xor(sum, off);
    if (lane == 0) y[r] = sum;
}

// ---------------------------------------------------------------------------
extern "C" void kernel_launch(void* const* d_in, const int* in_sizes, int n_in,
                              void* d_out, int out_size, void* d_ws, size_t ws_size,
                              hipStream_t stream) {
    const float* x   = (const float*)d_in[0];
    const float* Wq  = (const float*)d_in[1];
    const float* Wk  = (const float*)d_in[2];
    const float* Wv  = (const float*)d_in[3];
    const float* Wo  = (const float*)d_in[4];
    float*       kvk = (float*)d_in[5];
    float*       kvv = (float*)d_in[6];
    const int*   pos = (const int*)d_in[7];
    float* ws = (float*)d_ws;
    float* y  = (float*)d_out;

    proj_qkv   <<<512,  256, 0, stream>>>(x, Wq, Wk, Wv, kvk, kvv, pos, ws);
    attn_decode<<<2048, 256, 0, stream>>>(kvk, kvv, pos, ws);
    combine1   <<<384,   64, 0, stream>>>(ws);
    combine2   <<< 12,   64, 0, stream>>>(ws);
    proj_out   <<<384,  256, 0, stream>>>(Wo, ws, y);
}